// Round 16
// baseline (69.817 us; speedup 1.0000x reference)
//
#include <hip/hip_runtime.h>
#include <hip/hip_bf16.h>
#include <math.h>

typedef __attribute__((ext_vector_type(8))) short short8;
typedef __attribute__((ext_vector_type(4))) float f32x4;
typedef __attribute__((ext_vector_type(16))) float f32x16;
typedef __attribute__((ext_vector_type(4))) unsigned int uint4v;

constexpr int Hm = 512, Lm = 1024, Bm = 8;

static __device__ __forceinline__ unsigned short f2bf(float f) {
    __hip_bfloat16 h = __float2bfloat16(f);
    return *reinterpret_cast<unsigned short*>(&h);
}
static __device__ __forceinline__ float bf2f(unsigned short u) {
    return __uint_as_float((unsigned)u << 16);
}
static __device__ __forceinline__ uint2 pack4(const unsigned short* x) {
    return make_uint2((unsigned)x[0] | ((unsigned)x[1] << 16),
                      (unsigned)x[2] | ((unsigned)x[3] << 16));
}
static __device__ __forceinline__ short8 ld16u(const char* p) {   // 2 x b64
    uint2 a = *(const uint2*)p;
    uint2 b = *(const uint2*)(p + 8);
    uint4v t = { a.x, a.y, b.x, b.y };
    return __builtin_bit_cast(short8, t);
}

// FUSED: param math (f64) + K generation + conv_w cvt + Toeplitz block-conv.
// One block per h (256 thr, 4 waves). 8-replica b128 G layout (R15-proven).
__global__ __launch_bounds__(256, 2) void k_tconv(const float* __restrict__ log_dt,
                                                  const float* __restrict__ log_A_real,
                                                  const float* __restrict__ A_imag,
                                                  const float* __restrict__ B_real,
                                                  const float* __restrict__ B_imag,
                                                  const float* __restrict__ C_real,
                                                  const float* __restrict__ C_imag,
                                                  const float* __restrict__ conv_w,
                                                  const float* __restrict__ u,
                                                  const float* __restrict__ Dvec,
                                                  unsigned short* __restrict__ Woh,
                                                  unsigned short* __restrict__ YbfH,
                                                  unsigned int* __restrict__ counter) {
    __shared__ __align__(16) char smem[41984];
    const int tid = threadIdx.x, lane = tid & 63, w = tid >> 6;   // 4 waves
    const int h = blockIdx.x;
    const int m = lane & 31, q = lane >> 5;
    const int cg = (lane >> 3) & 3, b = lane & 7;
    float* Kf = (float*)(smem + 36352);   // [1024]
    float* pl = (float*)(smem + 40448);   // [6][64]

    if (h == 0 && tid == 0) *counter = 0;   // deterministic reset for k2's finalize

    // T14: issue u loads EARLY (held in regs across the rotation phase)
    float4 ureg[8];
    {
        const int b2 = tid >> 5, t32 = tid & 31;
        const float* ub = u + ((size_t)(b2 * 512 + h)) * 1024;
        #pragma unroll
        for (int g = 0; g < 8; ++g) ureg[g] = *(const float4*)&ub[t32 * 4 + g * 128];
    }
    const float Dh = Dvec[h];

    {   // conv_w bf16 cvt (hi only)
        int i = h * 1024 + tid * 4;
        float4 v = *(const float4*)&conv_w[i];
        *(uint2*)&Woh[i] = make_uint2((unsigned)f2bf(v.x) | ((unsigned)f2bf(v.y) << 16),
                                      (unsigned)f2bf(v.z) | ((unsigned)f2bf(v.w) << 16));
    }
    if (tid < 64) {   // param math (f64)
        int idx = h * 64 + tid;
        double dt = exp((double)log_dt[h]);
        double Ar = -exp((double)log_A_real[idx]);
        double Ai = (double)A_imag[idx];
        double ar = Ar * dt, ai = Ai * dt;
        double er = exp(ar);
        double rr = er * cos(ai), ri = er * sin(ai);
        double nr = rr - 1.0, ni = ri;
        double den = Ar * Ar + Ai * Ai;
        double qr = (nr * Ar + ni * Ai) / den;
        double qi = (ni * Ar - nr * Ai) / den;
        double Br = (double)B_real[idx], Bi = (double)B_imag[idx];
        double bbr = qr * Br - qi * Bi, bbi = qr * Bi + qi * Br;
        double Cr = (double)C_real[idx], Ci = (double)C_imag[idx];
        double wr = Cr * bbr - Ci * bbi, wi = Cr * bbi + Ci * bbr;
        double e64 = exp(ar * 64.0);
        double p64 = ai * 64.0;
        pl[0 * 64 + tid] = (float)rr;
        pl[1 * 64 + tid] = (float)ri;
        pl[2 * 64 + tid] = (float)wr;
        pl[3 * 64 + tid] = (float)wi;
        pl[4 * 64 + tid] = (float)(e64 * cos(p64));
        pl[5 * 64 + tid] = (float)(e64 * sin(p64));
    }
    __syncthreads();

    {   // K rotation: Kf[j] = Re(sum_n w_n r_n^j); kl scratch overlays u region
        float* kl = (float*)(smem + 17792) + w * 1056;   // [16][66] per wave
        const float rrf = pl[0 * 64 + lane], rif = pl[1 * 64 + lane];
        float pr = pl[2 * 64 + lane], pi = pl[3 * 64 + lane];   // w
        float br = pl[4 * 64 + lane], bi = pl[5 * 64 + lane];   // r^64
        int cc = w * 4;
        while (cc) {
            if (cc & 1) { float t_ = pr * br - pi * bi; pi = fmaf(pr, bi, pi * br); pr = t_; }
            float t2 = br * br - bi * bi; bi = 2.f * br * bi; br = t2;
            cc >>= 1;
        }
        const int jj = lane & 15, nq = lane >> 4;
        for (int qq = 0; qq < 16; ++qq) {
            #pragma unroll
            for (int j = 0; j < 16; ++j) {
                kl[j * 66 + lane] = pr;
                float t_ = pr * rrf - pi * rif; pi = fmaf(pr, rif, pi * rrf); pr = t_;
            }
            asm volatile("s_waitcnt lgkmcnt(0)" ::: "memory");
            float s0 = 0.f, s1 = 0.f;
            #pragma unroll
            for (int n = 0; n < 16; n += 4) {
                float2 a = *(const float2*)&kl[jj * 66 + nq * 16 + n];
                float2 b2 = *(const float2*)&kl[jj * 66 + nq * 16 + n + 2];
                s0 += a.x + a.y; s1 += b2.x + b2.y;
            }
            float s = s0 + s1;
            s += __shfl_xor(s, 16);
            s += __shfl_xor(s, 32);
            if (lane < 16) Kf[w * 256 + qq * 16 + jj] = s;
            asm volatile("s_waitcnt lgkmcnt(0)" ::: "memory");
        }
    }
    __syncthreads();

    // merged phase: pack G replicas + zero tile + u write-late (disjoint regions)
    {
        unsigned int* Gd = (unsigned int*)smem;
        for (int t = tid; t < 4448; t += 256) {
            int s = t / 556;
            int d = t - s * 556;
            int idx0 = 2 * d + s;
            float k0 = (idx0 < 1024) ? Kf[idx0] : 0.f;
            float k1 = (idx0 + 1 < 1024) ? Kf[idx0 + 1] : 0.f;
            Gd[t] = (unsigned)f2bf(k0) | ((unsigned)f2bf(k1) << 16);
        }
        if (tid < 8) { uint4 z = {0, 0, 0, 0}; ((uint4*)(smem + 36224))[tid] = z; }
        const int b2 = tid >> 5, t32 = tid & 31;
        #pragma unroll
        for (int g = 0; g < 8; ++g) {
            int s = t32 * 4 + g * 128;
            float4 v = ureg[g];
            unsigned short t0 = f2bf(v.x), t1 = f2bf(v.y), t2 = f2bf(v.z), t3 = f2bf(v.w);
            int jc = s >> 6, e = s & 63;
            *(uint2*)(smem + 17792 + jc * 1152 + b2 * 144 + e * 2) =
                make_uint2((unsigned)t0 | ((unsigned)t1 << 16),
                           (unsigned)t2 | ((unsigned)t3 << 16));
        }
    }
    __syncthreads();

    const int icg = (cg == 0) ? w : (cg == 1) ? 7 - w : (cg == 2) ? 8 + w : 15 - w;
    const int dmax = 15 - w;

    int aU = 17792 + icg * 1152 + b * 144 + q * 16;
    const int zl = 36224 + q * 16;

    const int sA = (7 - m) & 7;
    int baseH = sA * 2224 + (991 - m - sA + 8 * q) * 2;

    const f32x16 zacc = {};
    f32x16 acc0 = zacc, acc1 = zacc;

    short8 m2, m1, w0, w1, w2, w3;
#define LDA() { const char* pH = smem + baseH; \
        m2 = *(const short8*)(pH +   0); m1 = *(const short8*)(pH +  32); \
        w0 = *(const short8*)(pH +  64); w1 = *(const short8*)(pH +  96); \
        w2 = *(const short8*)(pH + 128); w3 = *(const short8*)(pH + 160); }
    LDA();

    for (int d = 0; d <= dmax; ++d) {
        const char* pb = smem + ((d <= icg) ? aU : zl);
        short8 b0 = *(const short8*)(pb +  0);
        short8 b1 = *(const short8*)(pb + 32);
        short8 b2 = *(const short8*)(pb + 64);
        short8 b3 = *(const short8*)(pb + 96);
        acc0 = __builtin_amdgcn_mfma_f32_32x32x16_bf16(w0, b0, acc0, 0, 0, 0);
        acc1 = __builtin_amdgcn_mfma_f32_32x32x16_bf16(m2, b0, acc1, 0, 0, 0);
        acc0 = __builtin_amdgcn_mfma_f32_32x32x16_bf16(w1, b1, acc0, 0, 0, 0);
        acc1 = __builtin_amdgcn_mfma_f32_32x32x16_bf16(m1, b1, acc1, 0, 0, 0);
        acc0 = __builtin_amdgcn_mfma_f32_32x32x16_bf16(w2, b2, acc0, 0, 0, 0);
        acc1 = __builtin_amdgcn_mfma_f32_32x32x16_bf16(w0, b2, acc1, 0, 0, 0);
        acc0 = __builtin_amdgcn_mfma_f32_32x32x16_bf16(w3, b3, acc0, 0, 0, 0);
        acc1 = __builtin_amdgcn_mfma_f32_32x32x16_bf16(w1, b3, acc1, 0, 0, 0);
        baseH -= 128; aU -= 1152;
        if (d < dmax) LDA();
    }
#undef LDA

    __syncthreads();   // G region dead -> Y bounce [16][8][68]

    #pragma unroll
    for (int mf = 0; mf < 2; ++mf) {
        const f32x16 ac = mf ? acc1 : acc0;
        #pragma unroll
        for (int rq = 0; rq < 4; ++rq) {
            const int row0 = mf * 32 + 8 * rq + 4 * q;
            uint2 uv2 = *(const uint2*)(smem + 17792 + icg * 1152 + b * 144 + row0 * 2);
            unsigned short us[4] = { (unsigned short)(uv2.x & 0xffff),
                                     (unsigned short)(uv2.x >> 16),
                                     (unsigned short)(uv2.y & 0xffff),
                                     (unsigned short)(uv2.y >> 16) };
            unsigned short oh[4];
            #pragma unroll
            for (int k = 0; k < 4; ++k) {
                float y = ac[rq * 4 + k] + Dh * bf2f(us[k]);
                float g = 0.5f * y * (1.0f + erff(y * 0.70710678118654752f));
                oh[k] = f2bf(g);
            }
            *(uint2*)(smem + icg * 1088 + b * 136 + row0 * 2) = pack4(oh);
        }
    }
    __syncthreads();
    {   // coalesced copy-out: Ybf[b][h][l]
        const int b2 = tid >> 5, t32 = tid & 31;
        unsigned short* dst = YbfH + ((size_t)(b2 * 512 + h)) * 1024;
        #pragma unroll
        for (int g = 0; g < 8; ++g) {
            int s = t32 * 4 + g * 128;
            int jc = s >> 6, e = s & 63;
            uint2 v = *(const uint2*)(smem + jc * 1088 + b2 * 136 + e * 2);
            *(uint2*)&dst[s] = v;
        }
    }
}

// W-hi bf16 MFMA GEMM, fused Y transpose, reg-double-buffered staging,
// XCD-swizzled grid, FUSED final reduction (last block writes d_out).
__global__ __launch_bounds__(256) void k2_gemm(const unsigned short* __restrict__ WbfH,
                                               const unsigned short* __restrict__ Ybf,
                                               const float* __restrict__ conv_b,
                                               const float* __restrict__ dec_w,
                                               const float* __restrict__ dec_b,
                                               float* __restrict__ partial,
                                               unsigned int* __restrict__ counter,
                                               float* __restrict__ out) {
    __shared__ unsigned short WTh[128][40];
    __shared__ unsigned short YT[128][44];
    __shared__ float red[4][64][20];
    __shared__ int last_flag;
    const int tid = threadIdx.x, lane = tid & 63, wid = tid >> 6;
    // XCD-bijective swizzle: each XCD gets 8 oblk x 8 (b,lblk) pairs
    const int bid = blockIdx.x;
    const int wsz = (bid & 7) * 64 + (bid >> 3);
    const int oblk = wsz & 7, pp = wsz >> 3;
    const int lblk = pp & 7, b = pp >> 3;
    const int o0 = oblk * 64, l0 = lblk * 128;
    const int fr = lane & 15, fq = lane >> 4;

    f32x4 acc[8][2] = {};

    const int srow = tid >> 1, skh = (tid & 1) * 16;
    const int grow = (srow < 64) ? (o0 + srow) : (512 + o0 + srow - 64);
    const size_t woff = (size_t)grow * 512 + skh;
    const int cp = tid & 15, lg = tid >> 4;
    const unsigned short* ysb = Ybf + ((size_t)(b * 512 + 2 * cp)) * 1024 + l0 + lg * 8;

    uint4 wc0 = *(const uint4*)(WbfH + woff);
    uint4 wc1 = *(const uint4*)(WbfH + woff + 8);
    uint4 yc0 = *(const uint4*)(ysb);
    uint4 yc1 = *(const uint4*)(ysb + 1024);

    for (int c0 = 0; c0 < 512; c0 += 32) {
        __syncthreads();
        *(uint4*)&WTh[srow][skh]     = wc0;
        *(uint4*)&WTh[srow][skh + 8] = wc1;
        {
            const unsigned int* a = (const unsigned int*)&yc0;
            const unsigned int* c = (const unsigned int*)&yc1;
            #pragma unroll
            for (int t2 = 0; t2 < 4; ++t2) {
                unsigned int lo = (a[t2] & 0xffffu) | (c[t2] << 16);
                unsigned int hi = (a[t2] >> 16) | (c[t2] & 0xffff0000u);
                *(unsigned int*)&YT[lg * 8 + 2 * t2][2 * cp] = lo;
                *(unsigned int*)&YT[lg * 8 + 2 * t2 + 1][2 * cp] = hi;
            }
        }
        if (c0 + 32 < 512) {
            wc0 = *(const uint4*)(WbfH + woff + c0 + 32);
            wc1 = *(const uint4*)(WbfH + woff + c0 + 40);
            const unsigned short* ysn = ysb + (size_t)(c0 + 32) * 1024;
            yc0 = *(const uint4*)(ysn);
            yc1 = *(const uint4*)(ysn + 1024);
        }
        __syncthreads();
        short8 b0h = ld16u((const char*)&YT[wid * 32 + fr][fq * 8]);
        short8 b1h = ld16u((const char*)&YT[wid * 32 + 16 + fr][fq * 8]);
        #pragma unroll
        for (int mf = 0; mf < 8; ++mf) {
            short8 ah = *(const short8*)&WTh[mf * 16 + fr][fq * 8];
            acc[mf][0] = __builtin_amdgcn_mfma_f32_16x16x32_bf16(ah, b0h, acc[mf][0], 0, 0, 0);
            acc[mf][1] = __builtin_amdgcn_mfma_f32_16x16x32_bf16(ah, b1h, acc[mf][1], 0, 0, 0);
        }
    }

    #pragma unroll
    for (int mf = 0; mf < 4; ++mf)
        #pragma unroll
        for (int j = 0; j < 4; ++j) {
            int ol = mf * 16 + fq * 4 + j;
            float ba = conv_b[o0 + ol];
            float bb = conv_b[512 + o0 + ol];
            float s = 0.f;
            #pragma unroll
            for (int nf = 0; nf < 2; ++nf) {
                float za = acc[mf][nf][j] + ba;
                float zb = acc[mf + 4][nf][j] + bb;
                s += za / (1.f + expf(-zb));
            }
            red[wid][ol][fr] = s;
        }
    __syncthreads();
    if (tid < 64) {
        float s = 0.f;
        #pragma unroll
        for (int w = 0; w < 4; ++w) {
            float4 r0 = *(const float4*)&red[w][tid][0];
            float4 r1 = *(const float4*)&red[w][tid][4];
            float4 r2 = *(const float4*)&red[w][tid][8];
            float4 r3 = *(const float4*)&red[w][tid][12];
            s += (r0.x + r0.y + r0.z + r0.w) + (r1.x + r1.y + r1.z + r1.w)
               + (r2.x + r2.y + r2.z + r2.w) + (r3.x + r3.y + r3.z + r3.w);
        }
        float val = s * dec_w[o0 + tid] * (1.0f / 1024.0f);
        #pragma unroll
        for (int off = 32; off; off >>= 1) val += __shfl_xor(val, off);
        if (tid == 0) {
            partial[((b * 8) + oblk) * 8 + lblk] = val;
            __threadfence();
            unsigned int prev = atomicAdd(counter, 1u);
            last_flag = (prev == 511u) ? 1 : 0;
        }
    }
    __syncthreads();
    if (last_flag && tid < 8) {   // final reduction (ex-k3), one block only
        __threadfence();
        volatile const float* vp = partial;
        float s = dec_b[0];
        for (int i = 0; i < 64; ++i) s += vp[tid * 64 + i];
        out[tid] = s;
    }
}

extern "C" void kernel_launch(void* const* d_in, const int* in_sizes, int n_in,
                              void* d_out, int out_size, void* d_ws, size_t ws_size,
                              hipStream_t stream) {
    const float* u          = (const float*)d_in[0];
    const float* log_dt     = (const float*)d_in[1];
    const float* log_A_real = (const float*)d_in[2];
    const float* A_imag     = (const float*)d_in[3];
    const float* B_real     = (const float*)d_in[4];
    const float* B_imag     = (const float*)d_in[5];
    const float* C_real     = (const float*)d_in[6];
    const float* C_imag     = (const float*)d_in[7];
    const float* Dvec       = (const float*)d_in[8];
    const float* conv_w     = (const float*)d_in[9];
    const float* conv_b     = (const float*)d_in[10];
    const float* dec_w      = (const float*)d_in[11];
    const float* dec_b      = (const float*)d_in[12];

    char* base = (char*)d_ws;
    unsigned short* YbfH  = (unsigned short*)base;                      // 8 MB
    unsigned short* Wh    = (unsigned short*)(base + 8388608);          // 1 MB
    float* partial        = (float*)(base + 9437184);                   // 2 KB
    unsigned int* counter = (unsigned int*)(base + 9439232);            // 4 B
    float* out            = (float*)d_out;

    k_tconv<<<512, 256, 0, stream>>>(log_dt, log_A_real, A_imag, B_real, B_imag,
                                     C_real, C_imag, conv_w, u, Dvec, Wh, YbfH,
                                     counter);
    k2_gemm<<<512, 256, 0, stream>>>(Wh, YbfH, conv_b, dec_w, dec_b,
                                     partial, counter, out);
}